// Round 4
// baseline (66.291 us; speedup 1.0000x reference)
//
#include <hip/hip_runtime.h>

constexpr int HW = 4096;   // 64*64
constexpr int CT = 31;     // time channels
constexpr int CZ = 32;     // hidden channels
constexpr int CP = 128;    // poi channels
constexpr int CO = 64;     // output channels

// block = 256 threads = 4 waves; wave w owns output channels [16w, 16w+16).
// block covers 128 consecutive pixels of one image (2 px per lane).
// grid = 32 images * 32 tiles = 1024 blocks (4 blocks/CU).
__global__ __launch_bounds__(256, 4)
void poi_fused3(const float* __restrict__ poi,
                const float* __restrict__ tin,
                const float* __restrict__ wm,
                const float* __restrict__ bm,
                const float* __restrict__ wf,
                const float* __restrict__ bf,
                const float* __restrict__ wc,
                const float* __restrict__ bc,
                float* __restrict__ out)
{
    __shared__ float s_t[128];

    const int tid  = threadIdx.x;
    const int lane = tid & 63;
    const int b    = blockIdx.x >> 5;            // 32 tiles per image
    const int px0  = (blockIdx.x & 31) << 7;     // 128-px tile base
    const int og   = __builtin_amdgcn_readfirstlane(tid >> 6) * 16;  // SGPR
    const int px   = px0 + lane * 2;

    const float* pp = poi + (size_t)b * CP * HW + px;

    // ---- prefetch poi channels 0..7 BEFORE stage 1 (latency hides under MLP) ----
    float2 pA[8], pB[8];
    #pragma unroll
    for (int j = 0; j < 8; ++j)
        pA[j] = *reinterpret_cast<const float2*>(pp + (size_t)j * HW);

    // ---- stage 1: t = relu(wf . relu(wm@time + bm) + bf), threads 0..127 ----
    if (tid < 128) {
        const float* tp = tin + (size_t)b * CT * HW + px0 + tid;
        float tr[CT];
        #pragma unroll
        for (int c = 0; c < CT; ++c) tr[c] = tp[(size_t)c * HW];  // coalesced
        float acc1 = bf[0];
        #pragma unroll
        for (int k = 0; k < CZ; ++k) {
            float z = bm[k];                                      // uniform s_load
            #pragma unroll
            for (int c = 0; c < CT; ++c)
                z = fmaf(wm[k * CT + c], tr[c], z);               // uniform s_load
            acc1 = fmaf(wf[k], fmaxf(z, 0.f), acc1);
        }
        s_t[tid] = fmaxf(acc1, 0.f);
    }
    __syncthreads();

    // ---- stage 2: out[o,px] = t[px] * (wc[o,:] . poi[:,px]) + bc[o] ----
    const float* wg = wc + (size_t)og * CP;      // uniform base -> s_load weights

    float2 acc[16];
    #pragma unroll
    for (int o = 0; o < 16; ++o) acc[o] = make_float2(0.f, 0.f);

    // explicit register double-buffer: 8 loads in flight during every FMA phase
    #pragma unroll
    for (int g = 0; g < 16; g += 2) {
        const int cA = g * 8;                    // pA holds channels cA..cA+7
        // issue next 8 loads (channels cA+8..cA+15) into pB
        #pragma unroll
        for (int j = 0; j < 8; ++j)
            pB[j] = *reinterpret_cast<const float2*>(pp + (size_t)(cA + 8 + j) * HW);
        // consume pA
        #pragma unroll
        for (int j = 0; j < 8; ++j) {
            #pragma unroll
            for (int o = 0; o < 16; ++o) {
                const float w = wg[o * CP + cA + j];              // uniform s_load
                acc[o].x = fmaf(w, pA[j].x, acc[o].x);
                acc[o].y = fmaf(w, pA[j].y, acc[o].y);
            }
        }
        // issue following 8 loads (channels cA+16..cA+23) into pA, if any
        if (g + 2 < 16) {
            #pragma unroll
            for (int j = 0; j < 8; ++j)
                pA[j] = *reinterpret_cast<const float2*>(pp + (size_t)(cA + 16 + j) * HW);
        }
        // consume pB
        #pragma unroll
        for (int j = 0; j < 8; ++j) {
            #pragma unroll
            for (int o = 0; o < 16; ++o) {
                const float w = wg[o * CP + cA + 8 + j];          // uniform s_load
                acc[o].x = fmaf(w, pB[j].x, acc[o].x);
                acc[o].y = fmaf(w, pB[j].y, acc[o].y);
            }
        }
    }

    // ---- epilogue ----
    const float2 tv = *reinterpret_cast<const float2*>(&s_t[lane * 2]);
    float* op = out + (size_t)b * CO * HW + (size_t)og * HW + px;
    #pragma unroll
    for (int o = 0; o < 16; ++o) {
        const float bias = bc[og + o];                            // uniform s_load
        float2 r;
        r.x = fmaf(tv.x, acc[o].x, bias);
        r.y = fmaf(tv.y, acc[o].y, bias);
        *reinterpret_cast<float2*>(op + (size_t)o * HW) = r;      // coalesced
    }
}

extern "C" void kernel_launch(void* const* d_in, const int* in_sizes, int n_in,
                              void* d_out, int out_size, void* d_ws, size_t ws_size,
                              hipStream_t stream) {
    const float* poi = (const float*)d_in[0];
    const float* tin = (const float*)d_in[1];
    const float* wm  = (const float*)d_in[2];
    const float* bm  = (const float*)d_in[3];
    const float* wf  = (const float*)d_in[4];
    const float* bf  = (const float*)d_in[5];
    const float* wc  = (const float*)d_in[6];
    const float* bc  = (const float*)d_in[7];
    float* out = (float*)d_out;

    hipLaunchKernelGGL(poi_fused3, dim3(1024), dim3(256), 0, stream,
                       poi, tin, wm, bm, wf, bf, wc, bc, out);
}

// Round 5
// 66.154 us; speedup vs baseline: 1.0021x; 1.0021x over previous
//
#include <hip/hip_runtime.h>
#include <stdint.h>

constexpr int HW = 4096;   // 64*64
constexpr int CT = 31;     // time channels
constexpr int CZ = 32;     // hidden channels
constexpr int CP = 128;    // poi channels
constexpr int CO = 64;     // output channels
constexpr int PX = 128;    // pixels per block tile
constexpr int KC = 32;     // poi channels per staged chunk (4 chunks)

// block = 256 threads = 4 waves; wave w owns output channels [16w,16w+16).
// poi tile staged through LDS double-buffer with async global_load_lds.
// grid = 32 images * 32 tiles = 1024 blocks = exactly 4 per CU.
__global__ __launch_bounds__(256, 4)
void poi_fused4(const float* __restrict__ poi,
                const float* __restrict__ tin,
                const float* __restrict__ wm,
                const float* __restrict__ bm,
                const float* __restrict__ wf,
                const float* __restrict__ bf,
                const float* __restrict__ wc,
                const float* __restrict__ bc,
                float* __restrict__ out)
{
    __shared__ float s_poi[2][KC][PX];   // 2 x 16 KiB, linear rows (gll requirement)
    __shared__ float s_t[PX];

    const int tid  = threadIdx.x;
    const int lane = tid & 63;
    const int wid  = __builtin_amdgcn_readfirstlane(tid >> 6);   // SGPR wave id
    const int b    = blockIdx.x >> 5;            // 32 tiles per image
    const int px0  = (blockIdx.x & 31) << 7;     // 128-px tile base

    const float* pbase = poi + (size_t)b * CP * HW + px0;

    // async-stage one 32-channel chunk into s_poi[buf]:
    // wave w covers rows [8w, 8w+8), 2 rows per width-16 instr (lane>>5 = row parity)
    auto stage = [&](int buf, int kc0) {
        #pragma unroll
        for (int i = 0; i < 4; ++i) {
            const int row = wid * 8 + i * 2;                       // wave-uniform
            const float* g = pbase + (size_t)(kc0 + row + (lane >> 5)) * HW
                                   + ((lane & 31) << 2);           // per-lane src
            __builtin_amdgcn_global_load_lds(
                (const __attribute__((address_space(1))) unsigned int*)g,
                (__attribute__((address_space(3))) unsigned int*)&s_poi[buf][row][0],
                16, 0, 0);
        }
    };

    // ---- issue chunk 0 BEFORE stage-1 MLP: its latency hides under the MLP ----
    stage(0, 0);

    // ---- stage 1: t = relu(wf . relu(wm@time + bm) + bf), threads 0..127 ----
    if (tid < 128) {
        const float* tp = tin + (size_t)b * CT * HW + px0 + tid;
        float tr[CT];
        #pragma unroll
        for (int c = 0; c < CT; ++c) tr[c] = tp[(size_t)c * HW];   // coalesced
        float acc1 = bf[0];
        #pragma unroll
        for (int k = 0; k < CZ; ++k) {
            float z = bm[k];                                       // uniform s_load
            #pragma unroll
            for (int c = 0; c < CT; ++c)
                z = fmaf(wm[k * CT + c], tr[c], z);                // uniform s_load
            acc1 = fmaf(wf[k], fmaxf(z, 0.f), acc1);
        }
        s_t[tid] = fmaxf(acc1, 0.f);
    }
    __syncthreads();   // chunk 0 resident, t resident

    // ---- stage 2: 2-phase pipelined GEMM, 2 px/lane, 16 o/wave ----
    const float* wg = wc + (size_t)(wid * 16) * CP;   // uniform weight base

    float2 acc[16];
    #pragma unroll
    for (int o = 0; o < 16; ++o) acc[o] = make_float2(0.f, 0.f);

    #pragma unroll
    for (int k = 0; k < 4; ++k) {
        if (k < 3) stage((k + 1) & 1, (k + 1) * KC);   // async prefetch next chunk
        const int buf = k & 1;
        #pragma unroll
        for (int c = 0; c < KC; ++c) {
            const float2 p =
                *reinterpret_cast<const float2*>(&s_poi[buf][c][lane * 2]);
            #pragma unroll
            for (int o = 0; o < 16; ++o) {
                const float w = wg[o * CP + k * KC + c];           // s_load_dwordx16
                acc[o].x = fmaf(w, p.x, acc[o].x);
                acc[o].y = fmaf(w, p.y, acc[o].y);
            }
        }
        __syncthreads();   // drains prefetch (mostly complete) + guards buffer reuse
    }

    // ---- epilogue: out[o,px] = t[px]*acc + bc[o] ----
    const float2 tv = *reinterpret_cast<const float2*>(&s_t[lane * 2]);
    float* op = out + (size_t)b * CO * HW + (size_t)(wid * 16) * HW + px0 + lane * 2;
    #pragma unroll
    for (int o = 0; o < 16; ++o) {
        const float bias = bc[wid * 16 + o];                       // uniform s_load
        float2 r;
        r.x = fmaf(tv.x, acc[o].x, bias);
        r.y = fmaf(tv.y, acc[o].y, bias);
        *reinterpret_cast<float2*>(op + (size_t)o * HW) = r;       // coalesced
    }
}

extern "C" void kernel_launch(void* const* d_in, const int* in_sizes, int n_in,
                              void* d_out, int out_size, void* d_ws, size_t ws_size,
                              hipStream_t stream) {
    const float* poi = (const float*)d_in[0];
    const float* tin = (const float*)d_in[1];
    const float* wm  = (const float*)d_in[2];
    const float* bm  = (const float*)d_in[3];
    const float* wf  = (const float*)d_in[4];
    const float* bf  = (const float*)d_in[5];
    const float* wc  = (const float*)d_in[6];
    const float* bc  = (const float*)d_in[7];
    float* out = (float*)d_out;

    hipLaunchKernelGGL(poi_fused4, dim3(1024), dim3(256), 0, stream,
                       poi, tin, wm, bm, wf, bf, wc, bc, out);
}